// Round 8
// baseline (93.436 us; speedup 1.0000x reference)
//
#include <hip/hip_runtime.h>
#include <math.h>

// ListwiseSmoothINDCGKLoss: bs x ll (16384 x 2048) fp32 scores + graded labels
// -> scalar sum(1 - ndcg@10).
//
// Structure: ONE WAVE OWNS ONE ROW (EPT=32), 4 independent waves per
// 256-thread block -> zero __syncthreads, zero LDS. Per-k reduction is a
// 6-step DPP add (row_shr:1,2,4,8 + row_bcast:15,31 -> total in lane 63),
// pure VALU, then v_readlane broadcast.
//
// Round-8 change: PIN the 32 exponentials with empty inline-asm "+v" right
// after computation. Rounds 5-7 showed the allocator is occupancy-greedy and
// NOT cap-bound (min_waves=2 allows 128 VGPRs, it still chose 68): it kept
// only w[32]+q[32] and REMATERIALIZED exp2 in the prod update (+32 trans ops
// /k/lane ~= +30% issue). The asm redefinition makes remat illegal: the
// post-pin value cannot be recomputed, so e[] must stay register-resident
// (peak ~112 < 128 cap). Tripwires: VGPR should rise to ~100-124; if
// WRITE_SIZE explodes the pin forced spills instead -> revert.
//
// Carried lessons:
//  - NO local arrays (rounds 2-3: scratch allocas -> GBs of spill traffic);
//    every per-element value is a named scalar via macro expansion.
//  - scale-invariant softmax: exact row max not needed, M_k = min(range,118)*0.9^k
//    is a safe upper bound (row-min of z is 0, |prod|<=0.9^k). No per-k max.
//  - IDCG closed-form from packed label histogram (labels are ints 0..4).
//  - no divides in the loop: v_rcp + reciprocal-log2 constants.

constexpr int LL      = 2048;
constexpr int THREADS = 256;  // 4 waves; wave w handles row blockIdx*4+w
constexpr int RPB     = 4;
constexpr int KTOP    = 10;
constexpr float ALPHA  = 10.0f;
constexpr float EPSF   = 1e-10f;
constexpr float LOG2E  = 1.44269504088896340736f;
constexpr float MCLAMP = 118.0f;

// 1 / log2(k+2), k = 0..9 (constexpr + unroll-constant index => immediates)
__device__ constexpr float INVDEN[KTOP] = {
    1.0f,                 0.6309297535714574f, 0.5f,                0.43067655807339306f,
    0.38685280723454163f, 0.356207187108022f,  0.3333333333333333f, 0.31546487678572877f,
    0.30102999566398114f, 0.2890648263178878f};

// ---- DPP wave64 reductions (result lands in lane 63) ----
template <int CTRL>
__device__ __forceinline__ float dpp_addf(float v) {
    return v + __int_as_float(__builtin_amdgcn_update_dpp(
                   0, __float_as_int(v), CTRL, 0xF, 0xF, false));
}
template <int CTRL>
__device__ __forceinline__ float dpp_minf(float v) {
    return fminf(v, __int_as_float(__builtin_amdgcn_update_dpp(
                        0x7F800000, __float_as_int(v), CTRL, 0xF, 0xF, false)));
}
template <int CTRL>
__device__ __forceinline__ float dpp_maxf(float v) {
    return fmaxf(v, __int_as_float(__builtin_amdgcn_update_dpp(
                        (int)0xFF800000, __float_as_int(v), CTRL, 0xF, 0xF, false)));
}
template <int CTRL>
__device__ __forceinline__ int dpp_addi(int v) {
    return v + __builtin_amdgcn_update_dpp(0, v, CTRL, 0xF, 0xF, false);
}

// row_shr:1,2,4,8 then row_bcast:15, row_bcast:31
#define WAVE_RED(OP, v)                                                     \
    v = OP<0x111>(v); v = OP<0x112>(v); v = OP<0x114>(v); v = OP<0x118>(v); \
    v = OP<0x142>(v); v = OP<0x143>(v);

__device__ __forceinline__ float rl63f(float v) {
    return __int_as_float(__builtin_amdgcn_readlane(__float_as_int(v), 63));
}

// chunk expander: 8 chunks x 4 scalars = 32 elements per lane
#define CH(F) F(0) F(1) F(2) F(3) F(4) F(5) F(6) F(7)

__global__ __launch_bounds__(THREADS, 2) void ndcg_loss_kernel(
    const float* __restrict__ s, const float* __restrict__ label,
    float* __restrict__ ws, float* __restrict__ out, int mode) {
    const int    lane = threadIdx.x & 63;
    const int    wave = threadIdx.x >> 6;
    const size_t row  = (size_t)blockIdx.x * RPB + wave;

    const float4* sp = (const float4*)(s + row * (size_t)LL);
    const float4* lp = (const float4*)(label + row * (size_t)LL);

    // coalesced loads: chunk c = 1 KB contiguous (64 lanes x 16 B)
#define LOADS(c) const float4 sA##c = sp[(c) * 64 + lane];
    CH(LOADS)
#define LOADL(c) const float4 qA##c = lp[(c) * 64 + lane];
    CH(LOADL)

    // ---- row min / max ----
    float mn = sA0.x, mx = sA0.x;
#define MM(c)                                                                  \
    mn = fminf(mn, fminf(fminf(sA##c.x, sA##c.y), fminf(sA##c.z, sA##c.w)));   \
    mx = fmaxf(mx, fmaxf(fmaxf(sA##c.x, sA##c.y), fmaxf(sA##c.z, sA##c.w)));
    CH(MM)
    WAVE_RED(dpp_minf, mn)
    WAVE_RED(dpp_maxf, mx)
    mn = rl63f(mn);
    mx = rl63f(mx);

    // ---- packed label histogram: hA = c0|c1<<16, hB = c2|c3<<16, hC = c4 ----
    int hA = 0, hB = 0, hC = 0;
#define H1(q)                                   \
    {                                           \
        const int li = (int)(q);                \
        hA += (li == 0) + ((li == 1) << 16);    \
        hB += (li == 2) + ((li == 3) << 16);    \
        hC += (li == 4);                        \
    }
#define HC(c) H1(qA##c.x) H1(qA##c.y) H1(qA##c.z) H1(qA##c.w)
    CH(HC)
    WAVE_RED(dpp_addi, hA)
    WAVE_RED(dpp_addi, hB)
    WAVE_RED(dpp_addi, hC)
    hA = __builtin_amdgcn_readlane(hA, 63);
    hB = __builtin_amdgcn_readlane(hB, 63);
    hC = __builtin_amdgcn_readlane(hC, 63);

    const int n4 = hC;
    const int n3 = n4 + (hB >> 16);
    const int n2 = n3 + (hB & 0xFFFF);
    const int n1 = n2 + (hA >> 16);
    float idcg = EPSF;
#pragma unroll
    for (int slot = 0; slot < KTOP; ++slot) {
        const int v = (slot < n4) + (slot < n3) + (slot < n2) + (slot < n1);
        idcg = fmaf((float)(1 << v), INVDEN[slot], idcg);
    }

    // ---- w = z*prod, initialized to z = (s - mn)*ALPHA*log2(e) ----
    const float Cc = ALPHA * LOG2E;
#define WD(c)                                                        \
    float w##c##x = (sA##c.x - mn) * Cc, w##c##y = (sA##c.y - mn) * Cc, \
          w##c##z = (sA##c.z - mn) * Cc, w##c##w = (sA##c.w - mn) * Cc;
    CH(WD)
    float M   = fminf((mx - mn) * Cc, MCLAMP);
    float dcg = EPSF;

#pragma unroll
    for (int k = 0; k < KTOP; ++k) {
#define ED(c)                                            \
    float e##c##x = __builtin_amdgcn_exp2f(w##c##x - M), \
          e##c##y = __builtin_amdgcn_exp2f(w##c##y - M), \
          e##c##z = __builtin_amdgcn_exp2f(w##c##z - M), \
          e##c##w = __builtin_amdgcn_exp2f(w##c##w - M);
        CH(ED)
        // PIN: opaque redefinition -> exp2 remat across the reduction illegal
#define PIN(c) asm("" : "+v"(e##c##x), "+v"(e##c##y), "+v"(e##c##z), "+v"(e##c##w));
        CH(PIN)
        float se = 0.0f, sle = 0.0f;
#define AC(c)                                                       \
    se += (e##c##x + e##c##y) + (e##c##z + e##c##w);                \
    sle += fmaf(qA##c.x, e##c##x, qA##c.y * e##c##y) +              \
           fmaf(qA##c.z, e##c##z, qA##c.w * e##c##w);
        CH(AC)
        WAVE_RED(dpp_addf, se)
        WAVE_RED(dpp_addf, sle)
        se  = rl63f(se);
        sle = rl63f(sle);

        const float inv = __builtin_amdgcn_rcpf(se);
        dcg = fmaf(__builtin_amdgcn_exp2f(sle * inv), INVDEN[k], dcg);

        // w' = w * (0.9 - e*inv)   [prod update folded into w]
#define UP(c)                                \
    w##c##x *= fmaf(e##c##x, -inv, 0.9f);    \
    w##c##y *= fmaf(e##c##y, -inv, 0.9f);    \
    w##c##z *= fmaf(e##c##z, -inv, 0.9f);    \
    w##c##w *= fmaf(e##c##w, -inv, 0.9f);
        CH(UP)
        M *= 0.9f;
    }

    if (lane == 0) {
        const float loss = 1.0f - dcg / idcg;
        if (mode) atomicAdd(out, loss);
        else      ws[row] = loss;
    }
}

__global__ __launch_bounds__(256) void reduce_sum_kernel(
    const float* __restrict__ w, float* __restrict__ out, int n4) {
    __shared__ float sb[4];
    float acc = 0.0f;
    const float4* w4 = (const float4*)w;
    for (int i = threadIdx.x; i < n4; i += 256) {
        const float4 v = w4[i];
        acc += (v.x + v.y) + (v.z + v.w);
    }
#pragma unroll
    for (int o = 32; o; o >>= 1) acc += __shfl_xor(acc, o, 64);
    if ((threadIdx.x & 63) == 0) sb[threadIdx.x >> 6] = acc;
    __syncthreads();
    if (threadIdx.x == 0) out[0] = (sb[0] + sb[1]) + (sb[2] + sb[3]);
}

__global__ void zero_out_kernel(float* out) { out[0] = 0.0f; }

extern "C" void kernel_launch(void* const* d_in, const int* in_sizes, int n_in,
                              void* d_out, int out_size, void* d_ws,
                              size_t ws_size, hipStream_t stream) {
    const float* s     = (const float*)d_in[0];
    const float* label = (const float*)d_in[1];
    float*       out   = (float*)d_out;
    const int    bs    = in_sizes[0] / LL;

    if ((bs % RPB) == 0 && ws_size >= (size_t)bs * sizeof(float)) {
        float* w = (float*)d_ws;
        ndcg_loss_kernel<<<bs / RPB, THREADS, 0, stream>>>(s, label, w, nullptr, 0);
        reduce_sum_kernel<<<1, 256, 0, stream>>>(w, out, bs / 4);
    } else {
        zero_out_kernel<<<1, 1, 0, stream>>>(out);
        ndcg_loss_kernel<<<bs / RPB, THREADS, 0, stream>>>(s, label, nullptr, out, 1);
    }
}

// Round 9
// 75.361 us; speedup vs baseline: 1.2399x; 1.2399x over previous
//
#include <hip/hip_runtime.h>
#include <math.h>

// ListwiseSmoothINDCGKLoss: bs x ll (16384 x 2048) fp32 scores + graded labels
// -> scalar sum(1 - ndcg@10).
//
// Structure: ONE WAVE OWNS ONE ROW (EPT=32), 4 independent waves per
// 256-thread block -> zero __syncthreads, zero LDS. Per-k reduction is a
// 6-step DPP add (row_shr:1,2,4,8 + row_bcast:15,31 -> total in lane 63),
// then v_readlane broadcast.
//
// Round-9 changes:
//  (a) VOLATILE pin of the exponentials. Round 8's non-volatile asm pin
//      failed because pure asm may be DUPLICATED: the compiler re-ran
//      exp2 + the empty asm at the second use (VGPR stayed 72). volatile
//      asm cannot be deleted or duplicated -> e[] must stay resident.
//  (b) Packed fp32 (VOP3P v_pk_add/mul/fma_f32, CDNA 2xFP32 path) for the
//      elementwise phases: w-M subtract 32->16 insts/k, se/sle accumulate
//      ~80->~34, prod-update 64->32. exp2 remains scalar VOP1.
// Transient peak ~110 VGPR (w32+q32+e32+acc+misc) under the (256,2) cap=128.
//
// Carried lessons:
//  - NO local arrays (rounds 2-3: scratch allocas -> GBs of spill traffic);
//    per-element values are named scalars/pairs via macro expansion.
//  - scale-invariant softmax: M_k = min(range,118)*0.9^k upper bound, no
//    per-k max reduction (row-min of z is 0, |prod|<=0.9^k).
//  - IDCG closed-form from packed label histogram (labels are ints 0..4).
//  - no divides in the loop: v_rcp + reciprocal-log2 constants.

typedef float v2f __attribute__((ext_vector_type(2)));

constexpr int LL      = 2048;
constexpr int THREADS = 256;  // 4 waves; wave w handles row blockIdx*4+w
constexpr int RPB     = 4;
constexpr int KTOP    = 10;
constexpr float ALPHA  = 10.0f;
constexpr float EPSF   = 1e-10f;
constexpr float LOG2E  = 1.44269504088896340736f;
constexpr float MCLAMP = 118.0f;

// 1 / log2(k+2), k = 0..9 (constexpr + unroll-constant index => immediates)
__device__ constexpr float INVDEN[KTOP] = {
    1.0f,                 0.6309297535714574f, 0.5f,                0.43067655807339306f,
    0.38685280723454163f, 0.356207187108022f,  0.3333333333333333f, 0.31546487678572877f,
    0.30102999566398114f, 0.2890648263178878f};

// ---- VOP3P packed fp32 helpers (deterministic codegen via inline asm) ----
__device__ __forceinline__ v2f pk_add(v2f a, v2f b) {
    v2f d; asm("v_pk_add_f32 %0, %1, %2" : "=v"(d) : "v"(a), "v"(b)); return d;
}
__device__ __forceinline__ v2f pk_mul(v2f a, v2f b) {
    v2f d; asm("v_pk_mul_f32 %0, %1, %2" : "=v"(d) : "v"(a), "v"(b)); return d;
}
__device__ __forceinline__ v2f pk_fma(v2f a, v2f b, v2f c) {
    v2f d; asm("v_pk_fma_f32 %0, %1, %2, %3" : "=v"(d) : "v"(a), "v"(b), "v"(c)); return d;
}

// ---- DPP wave64 reductions (result lands in lane 63) ----
template <int CTRL>
__device__ __forceinline__ float dpp_addf(float v) {
    return v + __int_as_float(__builtin_amdgcn_update_dpp(
                   0, __float_as_int(v), CTRL, 0xF, 0xF, false));
}
template <int CTRL>
__device__ __forceinline__ float dpp_minf(float v) {
    return fminf(v, __int_as_float(__builtin_amdgcn_update_dpp(
                        0x7F800000, __float_as_int(v), CTRL, 0xF, 0xF, false)));
}
template <int CTRL>
__device__ __forceinline__ float dpp_maxf(float v) {
    return fmaxf(v, __int_as_float(__builtin_amdgcn_update_dpp(
                        (int)0xFF800000, __float_as_int(v), CTRL, 0xF, 0xF, false)));
}
template <int CTRL>
__device__ __forceinline__ int dpp_addi(int v) {
    return v + __builtin_amdgcn_update_dpp(0, v, CTRL, 0xF, 0xF, false);
}

// row_shr:1,2,4,8 then row_bcast:15, row_bcast:31
#define WAVE_RED(OP, v)                                                     \
    v = OP<0x111>(v); v = OP<0x112>(v); v = OP<0x114>(v); v = OP<0x118>(v); \
    v = OP<0x142>(v); v = OP<0x143>(v);

__device__ __forceinline__ float rl63f(float v) {
    return __int_as_float(__builtin_amdgcn_readlane(__float_as_int(v), 63));
}

// chunk expander: 8 chunks x 4 scalars = 32 elements per lane
#define CH(F) F(0) F(1) F(2) F(3) F(4) F(5) F(6) F(7)

__global__ __launch_bounds__(THREADS, 2) void ndcg_loss_kernel(
    const float* __restrict__ s, const float* __restrict__ label,
    float* __restrict__ ws, float* __restrict__ out, int mode) {
    const int    lane = threadIdx.x & 63;
    const int    wave = threadIdx.x >> 6;
    const size_t row  = (size_t)blockIdx.x * RPB + wave;

    const float4* sp = (const float4*)(s + row * (size_t)LL);
    const float4* lp = (const float4*)(label + row * (size_t)LL);

    // coalesced loads: chunk c = 1 KB contiguous (64 lanes x 16 B)
#define LOADS(c) const float4 sA##c = sp[(c) * 64 + lane];
    CH(LOADS)
#define LOADL(c) const float4 qA##c = lp[(c) * 64 + lane];
    CH(LOADL)

    // ---- row min / max ----
    float mn = sA0.x, mx = sA0.x;
#define MM(c)                                                                  \
    mn = fminf(mn, fminf(fminf(sA##c.x, sA##c.y), fminf(sA##c.z, sA##c.w)));   \
    mx = fmaxf(mx, fmaxf(fmaxf(sA##c.x, sA##c.y), fmaxf(sA##c.z, sA##c.w)));
    CH(MM)
    WAVE_RED(dpp_minf, mn)
    WAVE_RED(dpp_maxf, mx)
    mn = rl63f(mn);
    mx = rl63f(mx);

    // ---- packed label histogram: hA = c0|c1<<16, hB = c2|c3<<16, hC = c4 ----
    int hA = 0, hB = 0, hC = 0;
#define H1(q)                                   \
    {                                           \
        const int li = (int)(q);                \
        hA += (li == 0) + ((li == 1) << 16);    \
        hB += (li == 2) + ((li == 3) << 16);    \
        hC += (li == 4);                        \
    }
#define HC(c) H1(qA##c.x) H1(qA##c.y) H1(qA##c.z) H1(qA##c.w)
    CH(HC)
    WAVE_RED(dpp_addi, hA)
    WAVE_RED(dpp_addi, hB)
    WAVE_RED(dpp_addi, hC)
    hA = __builtin_amdgcn_readlane(hA, 63);
    hB = __builtin_amdgcn_readlane(hB, 63);
    hC = __builtin_amdgcn_readlane(hC, 63);

    const int n4 = hC;
    const int n3 = n4 + (hB >> 16);
    const int n2 = n3 + (hB & 0xFFFF);
    const int n1 = n2 + (hA >> 16);
    float idcg = EPSF;
#pragma unroll
    for (int slot = 0; slot < KTOP; ++slot) {
        const int v = (slot < n4) + (slot < n3) + (slot < n2) + (slot < n1);
        idcg = fmaf((float)(1 << v), INVDEN[slot], idcg);
    }

    // ---- packed persistent state: w = z*prod (init z), q labels ----
    const float Cc = ALPHA * LOG2E;
#define WD(c)                                                              \
    v2f wL##c = {(sA##c.x - mn) * Cc, (sA##c.y - mn) * Cc};                \
    v2f wH##c = {(sA##c.z - mn) * Cc, (sA##c.w - mn) * Cc};                \
    const v2f qL##c = {qA##c.x, qA##c.y};                                  \
    const v2f qH##c = {qA##c.z, qA##c.w};
    CH(WD)
    float M   = fminf((mx - mn) * Cc, MCLAMP);
    float dcg = EPSF;

#pragma unroll
    for (int k = 0; k < KTOP; ++k) {
        const float nM  = -M;
        const v2f   nM2 = {nM, nM};
        // e = exp2(w - M); VOLATILE pin -> cannot be deleted or duplicated,
        // so e stays register-resident through the reduction to the update.
#define ED(c)                                                       \
    {                                                               \
        const v2f dL = pk_add(wL##c, nM2), dH = pk_add(wH##c, nM2); \
        eL##c.x = __builtin_amdgcn_exp2f(dL.x);                     \
        eL##c.y = __builtin_amdgcn_exp2f(dL.y);                     \
        eH##c.x = __builtin_amdgcn_exp2f(dH.x);                     \
        eH##c.y = __builtin_amdgcn_exp2f(dH.y);                     \
        asm volatile("" : "+v"(eL##c), "+v"(eH##c));                \
    }
#define EDECL(c) v2f eL##c, eH##c;
        CH(EDECL)
        CH(ED)

        v2f accA = {0.0f, 0.0f}, accB = {0.0f, 0.0f};
#define AC(c)                                          \
    accA = pk_add(accA, pk_add(eL##c, eH##c));         \
    accB = pk_fma(qL##c, eL##c,                        \
                  pk_fma(qH##c, eH##c, accB));
        CH(AC)
        float se  = accA.x + accA.y;
        float sle = accB.x + accB.y;
        WAVE_RED(dpp_addf, se)
        WAVE_RED(dpp_addf, sle)
        se  = rl63f(se);
        sle = rl63f(sle);

        const float inv = __builtin_amdgcn_rcpf(se);
        dcg = fmaf(__builtin_amdgcn_exp2f(sle * inv), INVDEN[k], dcg);

        // w' = w * (0.9 - e*inv)   [prod update folded into w]
        const float ninv = -inv;
        const v2f   niv2 = {ninv, ninv};
        const v2f   c09  = {0.9f, 0.9f};
#define UP(c)                                          \
    wL##c = pk_mul(wL##c, pk_fma(eL##c, niv2, c09));   \
    wH##c = pk_mul(wH##c, pk_fma(eH##c, niv2, c09));
        CH(UP)
        M *= 0.9f;
    }

    if (lane == 0) {
        const float loss = 1.0f - dcg / idcg;
        if (mode) atomicAdd(out, loss);
        else      ws[row] = loss;
    }
}

__global__ __launch_bounds__(256) void reduce_sum_kernel(
    const float* __restrict__ w, float* __restrict__ out, int n4) {
    __shared__ float sb[4];
    float acc = 0.0f;
    const float4* w4 = (const float4*)w;
    for (int i = threadIdx.x; i < n4; i += 256) {
        const float4 v = w4[i];
        acc += (v.x + v.y) + (v.z + v.w);
    }
#pragma unroll
    for (int o = 32; o; o >>= 1) acc += __shfl_xor(acc, o, 64);
    if ((threadIdx.x & 63) == 0) sb[threadIdx.x >> 6] = acc;
    __syncthreads();
    if (threadIdx.x == 0) out[0] = (sb[0] + sb[1]) + (sb[2] + sb[3]);
}

__global__ void zero_out_kernel(float* out) { out[0] = 0.0f; }

extern "C" void kernel_launch(void* const* d_in, const int* in_sizes, int n_in,
                              void* d_out, int out_size, void* d_ws,
                              size_t ws_size, hipStream_t stream) {
    const float* s     = (const float*)d_in[0];
    const float* label = (const float*)d_in[1];
    float*       out   = (float*)d_out;
    const int    bs    = in_sizes[0] / LL;

    if ((bs % RPB) == 0 && ws_size >= (size_t)bs * sizeof(float)) {
        float* w = (float*)d_ws;
        ndcg_loss_kernel<<<bs / RPB, THREADS, 0, stream>>>(s, label, w, nullptr, 0);
        reduce_sum_kernel<<<1, 256, 0, stream>>>(w, out, bs / 4);
    } else {
        zero_out_kernel<<<1, 1, 0, stream>>>(out);
        ndcg_loss_kernel<<<bs / RPB, THREADS, 0, stream>>>(s, label, nullptr, out, 1);
    }
}

// Round 10
// 53.366 us; speedup vs baseline: 1.7509x; 1.4122x over previous
//
#include <hip/hip_runtime.h>
#include <math.h>

// ListwiseSmoothINDCGKLoss: bs x ll (16384 x 2048) fp32 scores + graded labels
// -> scalar sum(1 - ndcg@10).
//
// Round-10 structure: ONE WAVE OWNS TWO ROWS (EPT=16 per row, both rows
// spread across all 64 lanes). Round 9 ended latency-bound: VALUBusy 55%,
// occupancy ~2.3 waves/SIMD, HBM 15% -- the serial per-k chain (12 dependent
// DPP reduction steps + readlane + rcp + exp2 + broadcast) dominates and
// can't be hidden by TLP alone. Two independent rows per wave give the
// scheduler a second ready chain to issue during every stall shadow.
// Register cost is UNCHANGED vs round 9 (w:32, q:32, e:32 floats per lane,
// now partitioned 16+16 between rows); elementwise work per wave unchanged.
//
// Carried techniques:
//  - packed VOP3P fp32 (v_pk_add/mul/fma) for all elementwise phases.
//  - VOLATILE asm pin of exponentials (non-volatile pin was duplicated along
//    with a remat'd exp2 -- round 8; volatile cannot be deleted/duplicated).
//  - scale-invariant softmax: M_k = min(range,118)*0.9^k bound, no per-k max.
//  - NO local arrays ever (rounds 2-3: scratch allocas -> GB spill traffic).
//  - IDCG closed-form from packed label histogram (labels are ints 0..4).
//  - DPP wave64 reductions (row_shr 1,2,4,8 + row_bcast 15,31), rcp not div.

typedef float v2f __attribute__((ext_vector_type(2)));

constexpr int LL      = 2048;
constexpr int THREADS = 256;  // 4 waves/block; each wave owns 2 rows
constexpr int RPB     = 8;    // rows per block
constexpr int KTOP    = 10;
constexpr float ALPHA  = 10.0f;
constexpr float EPSF   = 1e-10f;
constexpr float LOG2E  = 1.44269504088896340736f;
constexpr float MCLAMP = 118.0f;

// 1 / log2(k+2), k = 0..9 (constexpr + unroll-constant index => immediates)
__device__ constexpr float INVDEN[KTOP] = {
    1.0f,                 0.6309297535714574f, 0.5f,                0.43067655807339306f,
    0.38685280723454163f, 0.356207187108022f,  0.3333333333333333f, 0.31546487678572877f,
    0.30102999566398114f, 0.2890648263178878f};

// ---- VOP3P packed fp32 helpers ----
__device__ __forceinline__ v2f pk_add(v2f a, v2f b) {
    v2f d; asm("v_pk_add_f32 %0, %1, %2" : "=v"(d) : "v"(a), "v"(b)); return d;
}
__device__ __forceinline__ v2f pk_mul(v2f a, v2f b) {
    v2f d; asm("v_pk_mul_f32 %0, %1, %2" : "=v"(d) : "v"(a), "v"(b)); return d;
}
__device__ __forceinline__ v2f pk_fma(v2f a, v2f b, v2f c) {
    v2f d; asm("v_pk_fma_f32 %0, %1, %2, %3" : "=v"(d) : "v"(a), "v"(b), "v"(c)); return d;
}

// ---- DPP wave64 reductions (result lands in lane 63) ----
template <int CTRL>
__device__ __forceinline__ float dpp_addf(float v) {
    return v + __int_as_float(__builtin_amdgcn_update_dpp(
                   0, __float_as_int(v), CTRL, 0xF, 0xF, false));
}
template <int CTRL>
__device__ __forceinline__ float dpp_minf(float v) {
    return fminf(v, __int_as_float(__builtin_amdgcn_update_dpp(
                        0x7F800000, __float_as_int(v), CTRL, 0xF, 0xF, false)));
}
template <int CTRL>
__device__ __forceinline__ float dpp_maxf(float v) {
    return fmaxf(v, __int_as_float(__builtin_amdgcn_update_dpp(
                        (int)0xFF800000, __float_as_int(v), CTRL, 0xF, 0xF, false)));
}
template <int CTRL>
__device__ __forceinline__ int dpp_addi(int v) {
    return v + __builtin_amdgcn_update_dpp(0, v, CTRL, 0xF, 0xF, false);
}

// row_shr:1,2,4,8 then row_bcast:15, row_bcast:31
#define WAVE_RED(OP, v)                                                     \
    v = OP<0x111>(v); v = OP<0x112>(v); v = OP<0x114>(v); v = OP<0x118>(v); \
    v = OP<0x142>(v); v = OP<0x143>(v);

__device__ __forceinline__ float rl63f(float v) {
    return __int_as_float(__builtin_amdgcn_readlane(__float_as_int(v), 63));
}

__device__ __forceinline__ float idcg_from_hist(int hA, int hB, int hC) {
    const int n4 = hC;
    const int n3 = n4 + (hB >> 16);
    const int n2 = n3 + (hB & 0xFFFF);
    const int n1 = n2 + (hA >> 16);
    float idcg = EPSF;
#pragma unroll
    for (int slot = 0; slot < KTOP; ++slot) {
        const int v = (slot < n4) + (slot < n3) + (slot < n2) + (slot < n1);
        idcg = fmaf((float)(1 << v), INVDEN[slot], idcg);
    }
    return idcg;
}

// expander: 4 chunks x 2 rows (chunk c = 1 KB contiguous, EPT=16 per row)
#define FORALL(F) F(0,0) F(1,0) F(2,0) F(3,0) F(0,1) F(1,1) F(2,1) F(3,1)

__global__ __launch_bounds__(THREADS, 2) void ndcg_loss_kernel(
    const float* __restrict__ s, const float* __restrict__ label,
    float* __restrict__ ws, float* __restrict__ out, int mode) {
    const int    lane = threadIdx.x & 63;
    const int    wave = threadIdx.x >> 6;
    const size_t r0   = ((size_t)blockIdx.x * 4 + wave) * 2;

    const float4* sp0 = (const float4*)(s + r0 * (size_t)LL);
    const float4* lp0 = (const float4*)(label + r0 * (size_t)LL);
    const float4* sp1 = (const float4*)(s + (r0 + 1) * (size_t)LL);
    const float4* lp1 = (const float4*)(label + (r0 + 1) * (size_t)LL);

#define LOADS(c, R) const float4 sA##c##_##R = sp##R[(c) * 64 + lane];
    FORALL(LOADS)
#define LOADL(c, R) const float4 qA##c##_##R = lp##R[(c) * 64 + lane];
    FORALL(LOADL)

    // ---- row min / max (two independent DPP chains) ----
    float mn_0 = sA0_0.x, mx_0 = sA0_0.x;
    float mn_1 = sA0_1.x, mx_1 = sA0_1.x;
#define MM(c, R)                                                        \
    mn_##R = fminf(mn_##R, fminf(fminf(sA##c##_##R.x, sA##c##_##R.y),   \
                                 fminf(sA##c##_##R.z, sA##c##_##R.w))); \
    mx_##R = fmaxf(mx_##R, fmaxf(fmaxf(sA##c##_##R.x, sA##c##_##R.y),   \
                                 fmaxf(sA##c##_##R.z, sA##c##_##R.w)));
    FORALL(MM)
    WAVE_RED(dpp_minf, mn_0)
    WAVE_RED(dpp_maxf, mx_0)
    WAVE_RED(dpp_minf, mn_1)
    WAVE_RED(dpp_maxf, mx_1)
    mn_0 = rl63f(mn_0); mx_0 = rl63f(mx_0);
    mn_1 = rl63f(mn_1); mx_1 = rl63f(mx_1);

    // ---- packed label histograms ----
    int hA_0 = 0, hB_0 = 0, hC_0 = 0, hA_1 = 0, hB_1 = 0, hC_1 = 0;
#define H1(qv, R)                                 \
    {                                             \
        const int li = (int)(qv);                 \
        hA_##R += (li == 0) + ((li == 1) << 16);  \
        hB_##R += (li == 2) + ((li == 3) << 16);  \
        hC_##R += (li == 4);                      \
    }
#define HC(c, R) H1(qA##c##_##R.x, R) H1(qA##c##_##R.y, R) H1(qA##c##_##R.z, R) H1(qA##c##_##R.w, R)
    FORALL(HC)
    WAVE_RED(dpp_addi, hA_0)
    WAVE_RED(dpp_addi, hB_0)
    WAVE_RED(dpp_addi, hC_0)
    WAVE_RED(dpp_addi, hA_1)
    WAVE_RED(dpp_addi, hB_1)
    WAVE_RED(dpp_addi, hC_1)
    const float idcg_0 = idcg_from_hist(__builtin_amdgcn_readlane(hA_0, 63),
                                        __builtin_amdgcn_readlane(hB_0, 63),
                                        __builtin_amdgcn_readlane(hC_0, 63));
    const float idcg_1 = idcg_from_hist(__builtin_amdgcn_readlane(hA_1, 63),
                                        __builtin_amdgcn_readlane(hB_1, 63),
                                        __builtin_amdgcn_readlane(hC_1, 63));

    // ---- packed persistent state: w = z*prod (init z), q labels ----
    const float Cc = ALPHA * LOG2E;
#define WD(c, R)                                                               \
    v2f wL##c##_##R = {(sA##c##_##R.x - mn_##R) * Cc, (sA##c##_##R.y - mn_##R) * Cc}; \
    v2f wH##c##_##R = {(sA##c##_##R.z - mn_##R) * Cc, (sA##c##_##R.w - mn_##R) * Cc}; \
    const v2f qL##c##_##R = {qA##c##_##R.x, qA##c##_##R.y};                    \
    const v2f qH##c##_##R = {qA##c##_##R.z, qA##c##_##R.w};
    FORALL(WD)
    float M_0 = fminf((mx_0 - mn_0) * Cc, MCLAMP);
    float M_1 = fminf((mx_1 - mn_1) * Cc, MCLAMP);
    float dcg_0 = EPSF, dcg_1 = EPSF;

#pragma unroll
    for (int k = 0; k < KTOP; ++k) {
        const v2f nM2_0 = {-M_0, -M_0};
        const v2f nM2_1 = {-M_1, -M_1};
#define EDECL(c, R) v2f eL##c##_##R, eH##c##_##R;
        FORALL(EDECL)
        // e = exp2(w - M); volatile pin -> no deletion, no duplication
#define ED(c, R)                                                             \
    {                                                                        \
        const v2f dL = pk_add(wL##c##_##R, nM2_##R);                         \
        const v2f dH = pk_add(wH##c##_##R, nM2_##R);                         \
        eL##c##_##R.x = __builtin_amdgcn_exp2f(dL.x);                        \
        eL##c##_##R.y = __builtin_amdgcn_exp2f(dL.y);                        \
        eH##c##_##R.x = __builtin_amdgcn_exp2f(dH.x);                        \
        eH##c##_##R.y = __builtin_amdgcn_exp2f(dH.y);                        \
        asm volatile("" : "+v"(eL##c##_##R), "+v"(eH##c##_##R));             \
    }
        FORALL(ED)

        v2f accA_0 = {0.0f, 0.0f}, accB_0 = {0.0f, 0.0f};
        v2f accA_1 = {0.0f, 0.0f}, accB_1 = {0.0f, 0.0f};
#define AC(c, R)                                                        \
    accA_##R = pk_add(accA_##R, pk_add(eL##c##_##R, eH##c##_##R));      \
    accB_##R = pk_fma(qL##c##_##R, eL##c##_##R,                         \
                      pk_fma(qH##c##_##R, eH##c##_##R, accB_##R));
        FORALL(AC)

        float se_0  = accA_0.x + accA_0.y, sle_0 = accB_0.x + accB_0.y;
        float se_1  = accA_1.x + accA_1.y, sle_1 = accB_1.x + accB_1.y;
        WAVE_RED(dpp_addf, se_0)
        WAVE_RED(dpp_addf, sle_0)
        WAVE_RED(dpp_addf, se_1)
        WAVE_RED(dpp_addf, sle_1)
        se_0 = rl63f(se_0); sle_0 = rl63f(sle_0);
        se_1 = rl63f(se_1); sle_1 = rl63f(sle_1);

        const float inv_0 = __builtin_amdgcn_rcpf(se_0);
        const float inv_1 = __builtin_amdgcn_rcpf(se_1);
        dcg_0 = fmaf(__builtin_amdgcn_exp2f(sle_0 * inv_0), INVDEN[k], dcg_0);
        dcg_1 = fmaf(__builtin_amdgcn_exp2f(sle_1 * inv_1), INVDEN[k], dcg_1);

        const v2f niv2_0 = {-inv_0, -inv_0};
        const v2f niv2_1 = {-inv_1, -inv_1};
        const v2f c09    = {0.9f, 0.9f};
#define UP(c, R)                                                           \
    wL##c##_##R = pk_mul(wL##c##_##R, pk_fma(eL##c##_##R, niv2_##R, c09)); \
    wH##c##_##R = pk_mul(wH##c##_##R, pk_fma(eH##c##_##R, niv2_##R, c09));
        FORALL(UP)
        M_0 *= 0.9f;
        M_1 *= 0.9f;
    }

    if (lane == 0) {
        const float loss0 = 1.0f - dcg_0 / idcg_0;
        const float loss1 = 1.0f - dcg_1 / idcg_1;
        if (mode) {
            atomicAdd(out, loss0 + loss1);
        } else {
            ws[r0]     = loss0;
            ws[r0 + 1] = loss1;
        }
    }
}

__global__ __launch_bounds__(256) void reduce_sum_kernel(
    const float* __restrict__ w, float* __restrict__ out, int n4) {
    __shared__ float sb[4];
    float acc = 0.0f;
    const float4* w4 = (const float4*)w;
    for (int i = threadIdx.x; i < n4; i += 256) {
        const float4 v = w4[i];
        acc += (v.x + v.y) + (v.z + v.w);
    }
#pragma unroll
    for (int o = 32; o; o >>= 1) acc += __shfl_xor(acc, o, 64);
    if ((threadIdx.x & 63) == 0) sb[threadIdx.x >> 6] = acc;
    __syncthreads();
    if (threadIdx.x == 0) out[0] = (sb[0] + sb[1]) + (sb[2] + sb[3]);
}

__global__ void zero_out_kernel(float* out) { out[0] = 0.0f; }

extern "C" void kernel_launch(void* const* d_in, const int* in_sizes, int n_in,
                              void* d_out, int out_size, void* d_ws,
                              size_t ws_size, hipStream_t stream) {
    const float* s     = (const float*)d_in[0];
    const float* label = (const float*)d_in[1];
    float*       out   = (float*)d_out;
    const int    bs    = in_sizes[0] / LL;

    if ((bs % RPB) == 0 && ws_size >= (size_t)bs * sizeof(float)) {
        float* w = (float*)d_ws;
        ndcg_loss_kernel<<<bs / RPB, THREADS, 0, stream>>>(s, label, w, nullptr, 0);
        reduce_sum_kernel<<<1, 256, 0, stream>>>(w, out, bs / 4);
    } else {
        zero_out_kernel<<<1, 1, 0, stream>>>(out);
        ndcg_loss_kernel<<<bs / RPB, THREADS, 0, stream>>>(s, label, nullptr, out, 1);
    }
}